// Round 10
// baseline (305.608 us; speedup 1.0000x reference)
//
#include <hip/hip_runtime.h>
#include <hip/hip_bf16.h>

#define NN 50000      // nodes
#define RO 5          // original relations
#define RT 11         // total relations (2*RO+1)
#define FF 128        // feature dim (in == out)
#define EE 800000     // edges
#define EE2 (2 * EE)
#define NBINS (2 * RO * NN)          // 500000 segment bins (r<10)
#define SLOTS 32                     // fixed u16 slots per bin = one 64B line
#define DPB 16                       // dst rows per block (NN % DPB == 0 -> no bounds checks)
#define FILL_BLKS (EE2 / 256)             // 6250
#define FEAT_BLKS ((NN * FF / 4) / 256)   // 6250
#define WT_BLKS ((RT * FF * FF) / 256)    // 704

typedef unsigned short u16;
typedef unsigned int u32;
typedef __attribute__((ext_vector_type(4))) unsigned short u16x4;
typedef __attribute__((ext_vector_type(4))) unsigned int u32x4;
typedef __attribute__((ext_vector_type(8))) short bf16x8;   // 8 bf16 (4 VGPRs)
typedef __attribute__((ext_vector_type(4))) float f32x4;

// fp32 -> bf16 round-to-nearest-even
__device__ __forceinline__ u16 f2b(float x) {
  unsigned u = __float_as_uint(x);
  return (u16)((u + 0x7fffu + ((u >> 16) & 1u)) >> 16);
}

// ---- fused fill + prep ----
// Sections by blockIdx (fill FIRST: latency-bound scatter overlaps BW-bound prep):
//   [0, FILL_BLKS)                : bin fill, 1 message/thread (R9-proven)
//   [FILL_BLKS, +FEAT_BLKS)       : feature fp32->bf16 cast
//   [.., +WT_BLKS)                : weight transpose + 16B-XOR swizzle (root into r=10)
//   last block                    : zero feature row NN
__global__ __launch_bounds__(256) void pf_k(const int* __restrict__ g,
                                            const float* __restrict__ f,
                                            const float* __restrict__ w,
                                            const float* __restrict__ root,
                                            int* __restrict__ cur,
                                            u16* __restrict__ eidx,
                                            u16* __restrict__ fb,
                                            u16* __restrict__ wt) {
  const int b = blockIdx.x;
  if (b < FILL_BLKS) {                             // ---- fill fixed-slot bins ----
    const int m = b * 256 + threadIdx.x;
    int e, bin; u16 val;
    if (m < EE) {
      e = m;
      int s = g[3 * e], r = g[3 * e + 1], d = g[3 * e + 2];
      bin = r * NN + d; val = (u16)s;              // forward: rel, dst <- src
    } else {
      e = m - EE;
      int d2 = g[3 * e], r = g[3 * e + 1], s2 = g[3 * e + 2];
      bin = (r + RO) * NN + d2; val = (u16)s2;     // reversed: rel+RO, src <- dst
    }
    int pos = atomicAdd(&cur[bin], 1);
    if (pos < SLOTS) eidx[bin * SLOTS + pos] = val;
  } else if (b < FILL_BLKS + FEAT_BLKS) {          // ---- feature cast ----
    int i = (b - FILL_BLKS) * 256 + threadIdx.x;
    float4 v = reinterpret_cast<const float4*>(f)[i];
    u16x4 o;
    o.x = f2b(v.x); o.y = f2b(v.y); o.z = f2b(v.z); o.w = f2b(v.w);
    reinterpret_cast<u16x4*>(fb)[i] = o;
  } else if (b < FILL_BLKS + FEAT_BLKS + WT_BLKS) {  // ---- weights ----
    int idx = (b - FILL_BLKS - FEAT_BLKS) * 256 + threadIdx.x;  // r*16384 + k*128 + o
    int r = idx >> 14;
    int rem = idx & 16383;
    int k = rem >> 7;
    int o = rem & 127;
    float v = w[idx];
    if (r == 10) v += root[rem];
    int chunk = (k >> 3) ^ (o & 7);
    wt[(r << 14) + (o << 7) + (chunk << 3) + (k & 7)] = f2b(v);
  } else {                                         // ---- zero row at index NN ----
    if (threadIdx.x < 64) reinterpret_cast<u32*>(fb)[NN * 64 + threadIdx.x] = 0;
  }
}

#define ACCX(p) { a0 += __uint_as_float((p).x << 16); a1 += __uint_as_float((p).x & 0xffff0000u); \
                  a2 += __uint_as_float((p).y << 16); a3 += __uint_as_float((p).y & 0xffff0000u); \
                  a4 += __uint_as_float((p).z << 16); a5 += __uint_as_float((p).z & 0xffff0000u); \
                  a6 += __uint_as_float((p).w << 16); a7 += __uint_as_float((p).w & 0xffff0000u); }

// ---- fused segment-mean + GEMM: out = sum_r mean_r @ W_r + f @ (W10+root) ----
// DPB=16: block owns 16 dst rows; 16 quarter-waves each compute ONE mean row
// (one u32 slot-load, 4 gathers in flight), tile passes through 4 KB swizzled
// LDS into MFMA. 3125 blocks (= NN/16 exactly -> no bounds checks anywhere).
__global__ __launch_bounds__(256) void mg_k(const int* __restrict__ cnt,
                                            const u32* __restrict__ eidx32,
                                            const u32x4* __restrict__ fv4,
                                            const u16* __restrict__ fbf,
                                            const u16* __restrict__ wt,
                                            float* __restrict__ out) {
  __shared__ __align__(16) u32x4 Asw[DPB * 16];    // 4 KB swizzled A tile
  const int tid  = threadIdx.x;
  const int lane = tid & 63;
  const int wv   = tid >> 6;
  const int l15  = lane & 15;
  const int ko   = lane >> 4;                      // quarter id within wave (== k-subchunk)
  const int qid  = wv * 4 + ko;                    // 0..15 = A-tile row this quarter owns
  const int q16  = ko << 4;
  const int base = blockIdx.x * DPB;
  const int drow = base + qid;                     // always < NN

  f32x4 acc[2];
  acc[0] = (f32x4){0.f, 0.f, 0.f, 0.f};
  acc[1] = (f32x4){0.f, 0.f, 0.f, 0.f};

  for (int r = 0; r < 10; ++r) {
    // ---- mean of this quarter's segment ----
    const int seg = r * NN + drow;
    const int c = min(cnt[seg], SLOTS);
    const u32 sl = eidx32[seg * 16 + l15];         // slots 2*l15, 2*l15+1
    int cmax = c;
    cmax = max(cmax, __shfl_xor(cmax, 16));
    cmax = max(cmax, __shfl_xor(cmax, 32));        // wave-uniform max over 4 rows

    float a0 = 0.f, a1 = 0.f, a2 = 0.f, a3 = 0.f, a4 = 0.f, a5 = 0.f, a6 = 0.f, a7 = 0.f;
    for (int i = 0; i < cmax; i += 4) {
      u32 w0 = __shfl(sl, q16 + (i >> 1));         // slots i, i+1
      u32 w1 = __shfl(sl, q16 + (i >> 1) + 1);     // slots i+2, i+3
      int s0 = (i     < c) ? (int)(w0 & 0xffffu) : NN;   // clamp to zero row
      int s1 = (i + 1 < c) ? (int)(w0 >> 16)     : NN;
      int s2 = (i + 2 < c) ? (int)(w1 & 0xffffu) : NN;
      int s3 = (i + 3 < c) ? (int)(w1 >> 16)     : NN;
      u32x4 p0 = fv4[s0 * 16 + l15];
      u32x4 p1 = fv4[s1 * 16 + l15];
      u32x4 p2 = fv4[s2 * 16 + l15];
      u32x4 p3 = fv4[s3 * 16 + l15];
      ACCX(p0); ACCX(p1); ACCX(p2); ACCX(p3);
    }

    const float inv = (c > 0) ? 1.0f / (float)c : 0.0f;
    u32x4 m0;
    m0.x = (u32)f2b(a0 * inv) | ((u32)f2b(a1 * inv) << 16);
    m0.y = (u32)f2b(a2 * inv) | ((u32)f2b(a3 * inv) << 16);
    m0.z = (u32)f2b(a4 * inv) | ((u32)f2b(a5 * inv) << 16);
    m0.w = (u32)f2b(a6 * inv) | ((u32)f2b(a7 * inv) << 16);
    Asw[qid * 16 + (l15 ^ (qid & 7))] = m0;        // swizzled write (same XOR on read)
    __syncthreads();

    // ---- MFMA: C[16 x 128cols] += A(16x128) @ Wr(128x128-slice) ----
    const u16* wb = wt + (r << 14);
#pragma unroll
    for (int kc = 0; kc < 4; ++kc) {
      bf16x8 a = *reinterpret_cast<const bf16x8*>(
          &Asw[l15 * 16 + ((kc * 4 + ko) ^ (l15 & 7))]);
#pragma unroll
      for (int fr = 0; fr < 2; ++fr) {
        const int o = wv * 32 + fr * 16 + l15;
        bf16x8 bfrag = *reinterpret_cast<const bf16x8*>(
            wb + (o << 7) + (((kc * 4 + ko) ^ (o & 7)) << 3));
        acc[fr] = __builtin_amdgcn_mfma_f32_16x16x32_bf16(a, bfrag, acc[fr], 0, 0, 0);
      }
    }
    __syncthreads();
  }

  // ---- r == 10: A = features (root folded into Wt[10]) ----
  {
    const u16* wb = wt + (10 << 14);
#pragma unroll
    for (int kc = 0; kc < 4; ++kc) {
      bf16x8 a = *reinterpret_cast<const bf16x8*>(
          fbf + (long)(base + l15) * FF + kc * 32 + ko * 8);
#pragma unroll
      for (int fr = 0; fr < 2; ++fr) {
        const int o = wv * 32 + fr * 16 + l15;
        bf16x8 bfrag = *reinterpret_cast<const bf16x8*>(
            wb + (o << 7) + (((kc * 4 + ko) ^ (o & 7)) << 3));
        acc[fr] = __builtin_amdgcn_mfma_f32_16x16x32_bf16(a, bfrag, acc[fr], 0, 0, 0);
      }
    }
  }

  // ---- store: D layout col=lane&15, row=(lane>>4)*4+reg ----
#pragma unroll
  for (int fr = 0; fr < 2; ++fr)
#pragma unroll
    for (int q2 = 0; q2 < 4; ++q2)
      out[(base + ko * 4 + q2) * FF + wv * 32 + fr * 16 + l15] = acc[fr][q2];
}

extern "C" void kernel_launch(void* const* d_in, const int* in_sizes, int n_in,
                              void* d_out, int out_size, void* d_ws, size_t ws_size,
                              hipStream_t stream) {
  const int*   graph  = (const int*)d_in[0];
  const float* feat   = (const float*)d_in[1];
  const float* weight = (const float*)d_in[2];
  const float* root   = (const float*)d_in[3];
  float* out = (float*)d_out;
  char* ws = (char*)d_ws;

  // workspace layout (256B-aligned), ~47 MB total:
  u16* fbf  = (u16*)(ws);                       // (NN+1)*128*2 = 12,800,256 (+pad)
  u16* wt   = (u16*)(ws + 12800512);            // 11*128*128*2 =    360,448
  int* cur  = (int*)(ws + 13160960);            // NBINS*4      =  2,000,000 (+pad)
  u16* eidx = (u16*)(ws + 15161088);            // NBINS*32*2   = 32,000,000

  hipMemsetAsync(cur, 0, NBINS * sizeof(int), stream);
  pf_k<<<FILL_BLKS + FEAT_BLKS + WT_BLKS + 1, 256, 0, stream>>>(
      graph, feat, weight, root, cur, eidx, fbf, wt);
  mg_k<<<NN / DPB, 256, 0, stream>>>(cur, (const u32*)eidx,
                                     (const u32x4*)fbf, fbf, wt, out);
}

// Round 11
// 289.106 us; speedup vs baseline: 1.0571x; 1.0571x over previous
//
#include <hip/hip_runtime.h>
#include <hip/hip_bf16.h>

#define NN 50000      // nodes
#define RO 5          // original relations
#define RT 11         // total relations (2*RO+1)
#define FF 128        // feature dim (in == out)
#define EE 800000     // edges
#define EE2 (2 * EE)
#define NBINS (2 * RO * NN)          // 500000 segment bins (r<10)
#define SLOTS 16                     // u16 slots per bin = 32 B (dirty set fits per-XCD L2)
#define DPB 32                       // dst rows per block (R9-proven)
#define FILL_BLKS (EE2 / 256)             // 6250
#define FEAT_BLKS ((NN * FF / 4) / 256)   // 6250
#define WT_BLKS ((RT * FF * FF) / 256)    // 704

typedef unsigned short u16;
typedef unsigned int u32;
typedef __attribute__((ext_vector_type(4))) unsigned short u16x4;
typedef __attribute__((ext_vector_type(4))) unsigned int u32x4;
typedef __attribute__((ext_vector_type(8))) short bf16x8;   // 8 bf16 (4 VGPRs)
typedef __attribute__((ext_vector_type(4))) float f32x4;

// fp32 -> bf16 round-to-nearest-even
__device__ __forceinline__ u16 f2b(float x) {
  unsigned u = __float_as_uint(x);
  return (u16)((u + 0x7fffu + ((u >> 16) & 1u)) >> 16);
}

// ---- fused fill + prep ----
// Sections by blockIdx (fill FIRST: latency-bound scatter overlaps BW-bound prep):
//   [0, FILL_BLKS)                : bin fill, 1 message/thread
//   [FILL_BLKS, +FEAT_BLKS)       : feature fp32->bf16 cast
//   [.., +WT_BLKS)                : weight transpose + 16B-XOR swizzle (root into r=10)
//   last block                    : zero feature row NN
__global__ __launch_bounds__(256) void pf_k(const int* __restrict__ g,
                                            const float* __restrict__ f,
                                            const float* __restrict__ w,
                                            const float* __restrict__ root,
                                            int* __restrict__ cur,
                                            u16* __restrict__ eidx,
                                            u16* __restrict__ fb,
                                            u16* __restrict__ wt) {
  const int b = blockIdx.x;
  if (b < FILL_BLKS) {                             // ---- fill fixed-slot bins ----
    const int m = b * 256 + threadIdx.x;
    int e, bin; u16 val;
    if (m < EE) {
      e = m;
      int s = g[3 * e], r = g[3 * e + 1], d = g[3 * e + 2];
      bin = r * NN + d; val = (u16)s;              // forward: rel, dst <- src
    } else {
      e = m - EE;
      int d2 = g[3 * e], r = g[3 * e + 1], s2 = g[3 * e + 2];
      bin = (r + RO) * NN + d2; val = (u16)s2;     // reversed: rel+RO, src <- dst
    }
    int pos = atomicAdd(&cur[bin], 1);
    if (pos < SLOTS) eidx[bin * SLOTS + pos] = val;
  } else if (b < FILL_BLKS + FEAT_BLKS) {          // ---- feature cast ----
    int i = (b - FILL_BLKS) * 256 + threadIdx.x;
    float4 v = reinterpret_cast<const float4*>(f)[i];
    u16x4 o;
    o.x = f2b(v.x); o.y = f2b(v.y); o.z = f2b(v.z); o.w = f2b(v.w);
    reinterpret_cast<u16x4*>(fb)[i] = o;
  } else if (b < FILL_BLKS + FEAT_BLKS + WT_BLKS) {  // ---- weights ----
    int idx = (b - FILL_BLKS - FEAT_BLKS) * 256 + threadIdx.x;  // r*16384 + k*128 + o
    int r = idx >> 14;
    int rem = idx & 16383;
    int k = rem >> 7;
    int o = rem & 127;
    float v = w[idx];
    if (r == 10) v += root[rem];
    int chunk = (k >> 3) ^ (o & 7);
    wt[(r << 14) + (o << 7) + (chunk << 3) + (k & 7)] = f2b(v);
  } else {                                         // ---- zero row at index NN ----
    if (threadIdx.x < 64) reinterpret_cast<u32*>(fb)[NN * 64 + threadIdx.x] = 0;
  }
}

#define ACCX(p) { a0 += __uint_as_float((p).x << 16); a1 += __uint_as_float((p).x & 0xffff0000u); \
                  a2 += __uint_as_float((p).y << 16); a3 += __uint_as_float((p).y & 0xffff0000u); \
                  a4 += __uint_as_float((p).z << 16); a5 += __uint_as_float((p).z & 0xffff0000u); \
                  a6 += __uint_as_float((p).w << 16); a7 += __uint_as_float((p).w & 0xffff0000u); }
#define ACCY(p) { b0 += __uint_as_float((p).x << 16); b1 += __uint_as_float((p).x & 0xffff0000u); \
                  b2 += __uint_as_float((p).y << 16); b3 += __uint_as_float((p).y & 0xffff0000u); \
                  b4 += __uint_as_float((p).z << 16); b5 += __uint_as_float((p).z & 0xffff0000u); \
                  b6 += __uint_as_float((p).w << 16); b7 += __uint_as_float((p).w & 0xffff0000u); }

// ---- fused segment-mean + GEMM (R9-proven DPB=32 structure, SLOTS=16) ----
// Block owns 32 dst rows. Per relation: 16 quarter-waves each compute 2 mean
// rows (2 chains x 4-unroll = 8 gathers in flight), write the 32x128 tile into
// swizzled LDS, then 4 waves MFMA it against Wr (B frags from L2-hot wt).
__global__ __launch_bounds__(256) void mg_k(const int* __restrict__ cnt,
                                            const u32* __restrict__ eidx32,
                                            const u32x4* __restrict__ fv4,
                                            const u16* __restrict__ fbf,
                                            const u16* __restrict__ wt,
                                            float* __restrict__ out) {
  __shared__ __align__(16) u32x4 Asw[DPB * 16];    // 8 KB swizzled A tile
  const int tid  = threadIdx.x;
  const int lane = tid & 63;
  const int wv   = tid >> 6;
  const int l15  = lane & 15;
  const int ko   = lane >> 4;                      // quarter id within wave (== k-subchunk)
  const int qid  = wv * 4 + ko;                    // 0..15
  const int q16  = ko << 4;
  const int base = blockIdx.x * DPB;

  f32x4 acc[2][2];
#pragma unroll
  for (int i = 0; i < 2; ++i)
#pragma unroll
    for (int j = 0; j < 2; ++j) acc[i][j] = (f32x4){0.f, 0.f, 0.f, 0.f};

  const int row0 = qid * 2, row1 = row0 + 1;
  const int d0 = base + row0, d1 = base + row1;
  const bool v0 = d0 < NN, v1 = d1 < NN;

  for (int r = 0; r < 10; ++r) {
    // ---- mean of 2 segments per quarter-wave ----
    const int seg0 = v0 ? r * NN + d0 : 0;
    const int seg1 = v1 ? r * NN + d1 : 0;
    const int c0 = v0 ? min(cnt[seg0], SLOTS) : 0;
    const int c1 = v1 ? min(cnt[seg1], SLOTS) : 0;
    // bin slots: 8 u32 words; lanes q16..q16+7 hold them (dup on upper 8 lanes)
    const u32 sl0 = eidx32[seg0 * 8 + (l15 & 7)];
    const u32 sl1 = eidx32[seg1 * 8 + (l15 & 7)];
    int cmax = max(c0, c1);
    cmax = max(cmax, __shfl_xor(cmax, 16));
    cmax = max(cmax, __shfl_xor(cmax, 32));        // wave-uniform

    float a0 = 0.f, a1 = 0.f, a2 = 0.f, a3 = 0.f, a4 = 0.f, a5 = 0.f, a6 = 0.f, a7 = 0.f;
    float b0 = 0.f, b1 = 0.f, b2 = 0.f, b3 = 0.f, b4 = 0.f, b5 = 0.f, b6 = 0.f, b7 = 0.f;

    for (int i = 0; i < cmax; i += 4) {            // cmax <= 16 -> <= 4 iters
      u32 wa0 = __shfl(sl0, q16 + (i >> 1));       // slots i, i+1
      u32 wa1 = __shfl(sl0, q16 + (i >> 1) + 1);   // slots i+2, i+3
      u32 wb0 = __shfl(sl1, q16 + (i >> 1));
      u32 wb1 = __shfl(sl1, q16 + (i >> 1) + 1);
      int s0 = (i     < c0) ? (int)(wa0 & 0xffffu) : NN;   // clamp to zero row
      int s1 = (i + 1 < c0) ? (int)(wa0 >> 16)     : NN;
      int s2 = (i + 2 < c0) ? (int)(wa1 & 0xffffu) : NN;
      int s3 = (i + 3 < c0) ? (int)(wa1 >> 16)     : NN;
      int t0 = (i     < c1) ? (int)(wb0 & 0xffffu) : NN;
      int t1 = (i + 1 < c1) ? (int)(wb0 >> 16)     : NN;
      int t2 = (i + 2 < c1) ? (int)(wb1 & 0xffffu) : NN;
      int t3 = (i + 3 < c1) ? (int)(wb1 >> 16)     : NN;
      u32x4 p0 = fv4[s0 * 16 + l15];
      u32x4 p1 = fv4[s1 * 16 + l15];
      u32x4 p2 = fv4[s2 * 16 + l15];
      u32x4 p3 = fv4[s3 * 16 + l15];
      u32x4 p4 = fv4[t0 * 16 + l15];
      u32x4 p5 = fv4[t1 * 16 + l15];
      u32x4 p6 = fv4[t2 * 16 + l15];
      u32x4 p7 = fv4[t3 * 16 + l15];
      ACCX(p0); ACCX(p1); ACCX(p2); ACCX(p3);
      ACCY(p4); ACCY(p5); ACCY(p6); ACCY(p7);
    }

    const float i0 = (c0 > 0) ? 1.0f / (float)c0 : 0.0f;
    const float i1 = (c1 > 0) ? 1.0f / (float)c1 : 0.0f;
    u32x4 m0, m1;
    m0.x = (u32)f2b(a0 * i0) | ((u32)f2b(a1 * i0) << 16);
    m0.y = (u32)f2b(a2 * i0) | ((u32)f2b(a3 * i0) << 16);
    m0.z = (u32)f2b(a4 * i0) | ((u32)f2b(a5 * i0) << 16);
    m0.w = (u32)f2b(a6 * i0) | ((u32)f2b(a7 * i0) << 16);
    m1.x = (u32)f2b(b0 * i1) | ((u32)f2b(b1 * i1) << 16);
    m1.y = (u32)f2b(b2 * i1) | ((u32)f2b(b3 * i1) << 16);
    m1.z = (u32)f2b(b4 * i1) | ((u32)f2b(b5 * i1) << 16);
    m1.w = (u32)f2b(b6 * i1) | ((u32)f2b(b7 * i1) << 16);
    Asw[row0 * 16 + (l15 ^ (row0 & 7))] = m0;      // swizzled write (rule 21:
    Asw[row1 * 16 + (l15 ^ (row1 & 7))] = m1;      //  same XOR on read side)
    __syncthreads();

    // ---- MFMA: C[32 x 32cols] += A(32x128) @ Wr(128x32) ----
    const u16* wb = wt + (r << 14);
#pragma unroll
    for (int kc = 0; kc < 4; ++kc) {
      bf16x8 afr[2];
#pragma unroll
      for (int fq = 0; fq < 2; ++fq) {
        const int arow = fq * 16 + l15;
        afr[fq] = *reinterpret_cast<const bf16x8*>(
            &Asw[arow * 16 + ((kc * 4 + ko) ^ (arow & 7))]);
      }
#pragma unroll
      for (int fr = 0; fr < 2; ++fr) {
        const int o = wv * 32 + fr * 16 + l15;     // o&7 == l15&7
        bf16x8 b = *reinterpret_cast<const bf16x8*>(
            wb + (o << 7) + (((kc * 4 + ko) ^ (o & 7)) << 3));
        acc[0][fr] = __builtin_amdgcn_mfma_f32_16x16x32_bf16(afr[0], b, acc[0][fr], 0, 0, 0);
        acc[1][fr] = __builtin_amdgcn_mfma_f32_16x16x32_bf16(afr[1], b, acc[1][fr], 0, 0, 0);
      }
    }
    __syncthreads();
  }

  // ---- r == 10: A = features (root folded into Wt[10]) ----
  {
    const u16* wb = wt + (10 << 14);
#pragma unroll
    for (int kc = 0; kc < 4; ++kc) {
      bf16x8 afr[2];
#pragma unroll
      for (int fq = 0; fq < 2; ++fq) {
        int rowg = base + fq * 16 + l15;
        rowg = (rowg < NN) ? rowg : NN;            // zero row for OOB
        afr[fq] = *reinterpret_cast<const bf16x8*>(
            fbf + (long)rowg * FF + kc * 32 + ko * 8);
      }
#pragma unroll
      for (int fr = 0; fr < 2; ++fr) {
        const int o = wv * 32 + fr * 16 + l15;
        bf16x8 b = *reinterpret_cast<const bf16x8*>(
            wb + (o << 7) + (((kc * 4 + ko) ^ (o & 7)) << 3));
        acc[0][fr] = __builtin_amdgcn_mfma_f32_16x16x32_bf16(afr[0], b, acc[0][fr], 0, 0, 0);
        acc[1][fr] = __builtin_amdgcn_mfma_f32_16x16x32_bf16(afr[1], b, acc[1][fr], 0, 0, 0);
      }
    }
  }

  // ---- store: D layout col=lane&15, row=(lane>>4)*4+reg ----
#pragma unroll
  for (int fq = 0; fq < 2; ++fq)
#pragma unroll
    for (int fr = 0; fr < 2; ++fr)
#pragma unroll
      for (int q2 = 0; q2 < 4; ++q2) {
        const int row = base + fq * 16 + ko * 4 + q2;
        if (row < NN) out[row * FF + wv * 32 + fr * 16 + l15] = acc[fq][fr][q2];
      }
}

extern "C" void kernel_launch(void* const* d_in, const int* in_sizes, int n_in,
                              void* d_out, int out_size, void* d_ws, size_t ws_size,
                              hipStream_t stream) {
  const int*   graph  = (const int*)d_in[0];
  const float* feat   = (const float*)d_in[1];
  const float* weight = (const float*)d_in[2];
  const float* root   = (const float*)d_in[3];
  float* out = (float*)d_out;
  char* ws = (char*)d_ws;

  // workspace layout (256B-aligned), ~31 MB total:
  u16* fbf  = (u16*)(ws);                       // (NN+1)*128*2 = 12,800,256 (+pad)
  u16* wt   = (u16*)(ws + 12800512);            // 11*128*128*2 =    360,448
  int* cur  = (int*)(ws + 13160960);            // NBINS*4      =  2,000,000 (+pad)
  u16* eidx = (u16*)(ws + 15161088);            // NBINS*16*2   = 16,000,000

  hipMemsetAsync(cur, 0, NBINS * sizeof(int), stream);
  pf_k<<<FILL_BLKS + FEAT_BLKS + WT_BLKS + 1, 256, 0, stream>>>(
      graph, feat, weight, root, cur, eidx, fbf, wt);
  mg_k<<<(NN + DPB - 1) / DPB, 256, 0, stream>>>(cur, (const u32*)eidx,
                                                 (const u32x4*)fbf, fbf, wt, out);
}